// Round 5
// baseline (629.172 us; speedup 1.0000x reference)
//
#include <hip/hip_runtime.h>

// Problem constants (QuantLinear: x[M,K] fp32, qweight[K,N/8] i32, qzeros[G,N/8] i32,
// scales[G,N] fp32, bias[N] fp32, groupsize=128) -> out[M,N] fp32
#define M_DIM 4096
#define N_DIM 12288
#define K_DIM 4096
#define NP    1536        // N/8 packed words per row
#define GS    128

typedef unsigned short ushort_t;
typedef _Float16 half8 __attribute__((ext_vector_type(8)));
typedef unsigned short us8 __attribute__((ext_vector_type(8)));
typedef unsigned short us16 __attribute__((ext_vector_type(16)));
typedef float f32x16 __attribute__((ext_vector_type(16)));
typedef float f32x4 __attribute__((ext_vector_type(4)));

__device__ __forceinline__ unsigned short f2h(float f) {
  _Float16 h = (_Float16)f;
  return __builtin_bit_cast(unsigned short, h);
}

// async global->LDS, 16B per lane; LDS dst is wave-uniform base + lane*16
#define GLDS16(G, L) __builtin_amdgcn_global_load_lds(                      \
    (const __attribute__((address_space(1))) void*)(G),                     \
    (__attribute__((address_space(3))) void*)(L), 16, 0, 0)

// Tiled workspace layout ("unit" = 32-k step of one 256-row panel):
//   unit image = 16KB = [slice s:2][row r:256][slot t0:2][8 f16]
//   halfword offset  = s*4096 + r*16 + t0*8
//   content          = operand[panel*256 + r][u*32 + s*16 + (t0^((r>>2)&1))*8 + j]
// Byte-identical to what the GEMM's stage places in LDS -> glds source is
// unit_base + tid*16B (linear); read side keeps the measured-conflict-free
// R5/R7 addressing.
// WtT: 48 n-panels x 128 units; XbT: 16 m-panels x 128 units.

#define DQ_BLOCKS (48 * 128)     // 6144: one B-unit each
#define CVT_BLOCKS (16 * 128)    // 2048: one A-unit each

// ---------------------------------------------------------------------------
// Fused prep. DQ blocks: dequant qweight -> WtT tiled units. CVT blocks:
// x fp32 -> f16 XbT tiled units. R8: nontemporal stores on all workspace
// writes (write-allocate/RFO theory — FETCH evidence from the gemm dispatch
// suggests partial/streaming stores trigger line allocation reads).
__global__ __launch_bounds__(256) void prep_kernel(
    const int* __restrict__ qw, const int* __restrict__ qz,
    const float* __restrict__ sc, ushort_t* __restrict__ wtT,
    const float* __restrict__ x, ushort_t* __restrict__ xbT) {
  __shared__ int ldsQ[32 * 32];
  __shared__ int ldsZ[32];
  const int tid = threadIdx.x;
  const int bx  = blockIdx.x;
  if (bx >= DQ_BLOCKS) {
    // ---- x fp32 -> f16 into tiled A-unit (pm, u)
    const int idx = bx - DQ_BLOCKS;
    const int pm = idx >> 7, u = idx & 127;
    const int r  = tid;                  // m-local 0..255
    const int rb = (r >> 2) & 1;
    const float* src = x + (size_t)(pm * 256 + r) * K_DIM + u * 32;
    ushort_t* dst = xbT + (size_t)(pm * 128 + u) * 8192 + r * 16;
#pragma unroll
    for (int sl = 0; sl < 2; ++sl) {
      float4 f0 = *(const float4*)(src + sl * 16);
      float4 f1 = *(const float4*)(src + sl * 16 + 4);
      float4 f2 = *(const float4*)(src + sl * 16 + 8);
      float4 f3 = *(const float4*)(src + sl * 16 + 12);
      us8 lo, hi;
      lo[0] = f2h(f0.x); lo[1] = f2h(f0.y); lo[2] = f2h(f0.z); lo[3] = f2h(f0.w);
      lo[4] = f2h(f1.x); lo[5] = f2h(f1.y); lo[6] = f2h(f1.z); lo[7] = f2h(f1.w);
      hi[0] = f2h(f2.x); hi[1] = f2h(f2.y); hi[2] = f2h(f2.z); hi[3] = f2h(f2.w);
      hi[4] = f2h(f3.x); hi[5] = f2h(f3.y); hi[6] = f2h(f3.z); hi[7] = f2h(f3.w);
      us8 s0 = rb ? hi : lo;             // slot t0 holds k-half t0^rb
      us8 s1 = rb ? lo : hi;
      us16 o = __builtin_shufflevector(s0, s1, 0, 1, 2, 3, 4, 5, 6, 7,
                                       8, 9, 10, 11, 12, 13, 14, 15);
      __builtin_nontemporal_store(o, (us16*)(dst + sl * 4096));
    }
    return;
  }
  // ---- dequant B-unit (p, u): 256 n x 32 k
  const int p  = bx >> 7;          // n-panel 0..47
  const int u  = bx & 127;         // k-unit 0..127
  const int w0 = p << 5;           // first packed word col (32 words = 256 n)
  const int g  = u >> 2;           // 32-k unit inside one 128-group
  const int kb = u << 5;
  {
    // stage qw [32 rows][32 words], XOR'd for conflict-free transposed read
    int row = tid >> 3, wq = tid & 7;
    int4 v = *(const int4*)(qw + (size_t)(kb + row) * NP + w0 + wq * 4);
    ldsQ[row * 32 + ((wq * 4 + 0) ^ row)] = v.x;
    ldsQ[row * 32 + ((wq * 4 + 1) ^ row)] = v.y;
    ldsQ[row * 32 + ((wq * 4 + 2) ^ row)] = v.z;
    ldsQ[row * 32 + ((wq * 4 + 3) ^ row)] = v.w;
  }
  if (tid < 32) ldsZ[tid] = qz[(size_t)g * NP + w0 + tid];
  __syncthreads();
  const int r   = tid;             // n-local 0..255
  const int col = r >> 3;
  const int j4  = (r & 7) * 4;
  const int rb  = (r >> 2) & 1;
  const int z   = (ldsZ[col] >> j4) & 0xF;
  const float s = sc[(size_t)g * N_DIM + p * 256 + r];
  ushort_t* dst = wtT + (size_t)(p * 128 + u) * 8192 + r * 16;
#pragma unroll
  for (int sl = 0; sl < 2; ++sl) {
    us8 e0, e1;                    // k-halves 0 (sl*16+0..7) and 1 (sl*16+8..15)
#pragma unroll
    for (int j = 0; j < 8; ++j) {
      int k0 = sl * 16 + j;
      int k1 = k0 + 8;
      int q0 = (ldsQ[k0 * 32 + (col ^ k0)] >> j4) & 0xF;
      int q1 = (ldsQ[k1 * 32 + (col ^ k1)] >> j4) & 0xF;
      e0[j] = f2h((float)(q0 - z) * s);
      e1[j] = f2h((float)(q1 - z) * s);
    }
    us8 s0 = rb ? e1 : e0;         // slot t0 holds k-half t0^rb
    us8 s1 = rb ? e0 : e1;
    us16 o = __builtin_shufflevector(s0, s1, 0, 1, 2, 3, 4, 5, 6, 7,
                                     8, 9, 10, 11, 12, 13, 14, 15);
    __builtin_nontemporal_store(o, (us16*)(dst + sl * 4096));
  }
}

// ---------------------------------------------------------------------------
// R8 GEMM: R7 structure (340us, MfmaUtil 58%, conflicts 0) with PER-MFMA
// counted lgkm waits. R7's row-level waits exposed ~480cy of post-barrier
// LDS queue (first MFMA needed 5 reads = 40 CU-wide). Now the first MFMA
// fires after 2 reads land (lgkmcnt(10)), and each subsequent MFMA's wait
// covers exactly the reads it consumes — the drain hides under the MFMA
// stream. Everything else (ring-4 of 32k units, stage at phase start,
// end-of-phase vmcnt(8)+single barrier, epilogue wait taper) unchanged.
//
// 256x256 tile, BK=64, 512 threads = 8 waves (2m x 4n), wave tile 128x64 of
// mfma_f32_16x16x32_f16. Issue order (SB-pinned): af0,bf0,bf1,bf2,bf3,
// af1..af7 (reads 1..12). Wait map: MFMA(0,0)@10 (0,1)@9 (0,2)@8 (0,3)@7,
// row i>=1 @ 7-i.

__device__ __forceinline__ void stage_unit(
    int u, const ushort_t* __restrict__ AT, const ushort_t* __restrict__ BT,
    int pm, int pn, int tid, ushort_t* lds) {
  const int b  = (u >> 1) & 1;
  const int ks = u & 1;
  ushort_t* dA = lds + b * 32768 + ks * 8192 + tid * 8;
  ushort_t* dB = dA + 16384;
  const ushort_t* sA = AT + (size_t)(pm * 128 + u) * 8192 + tid * 8;
  const ushort_t* sB = BT + (size_t)(pn * 128 + u) * 8192 + tid * 8;
  GLDS16(sA,        dA);          // A slice 0
  GLDS16(sA + 4096, dA + 4096);   // A slice 1
  GLDS16(sB,        dB);          // B slice 0
  GLDS16(sB + 4096, dB + 4096);   // B slice 1
}

template <int N>
__device__ __forceinline__ void wait_lgkm() {
  if constexpr (N == 0)       asm volatile("s_waitcnt lgkmcnt(0)" ::: "memory");
  else if constexpr (N == 1)  asm volatile("s_waitcnt lgkmcnt(1)" ::: "memory");
  else if constexpr (N == 2)  asm volatile("s_waitcnt lgkmcnt(2)" ::: "memory");
  else if constexpr (N == 3)  asm volatile("s_waitcnt lgkmcnt(3)" ::: "memory");
  else if constexpr (N == 4)  asm volatile("s_waitcnt lgkmcnt(4)" ::: "memory");
  else if constexpr (N == 5)  asm volatile("s_waitcnt lgkmcnt(5)" ::: "memory");
  else if constexpr (N == 6)  asm volatile("s_waitcnt lgkmcnt(6)" ::: "memory");
  else if constexpr (N == 7)  asm volatile("s_waitcnt lgkmcnt(7)" ::: "memory");
  else if constexpr (N == 8)  asm volatile("s_waitcnt lgkmcnt(8)" ::: "memory");
  else if constexpr (N == 9)  asm volatile("s_waitcnt lgkmcnt(9)" ::: "memory");
  else if constexpr (N == 10) asm volatile("s_waitcnt lgkmcnt(10)" ::: "memory");
  __builtin_amdgcn_sched_barrier(0);   // rule 18: keep MFMAs below the wait
}

#define SB() __builtin_amdgcn_sched_barrier(0)

template <int VN, bool STG>
__device__ __forceinline__ void gemm_phase(
    int p, const ushort_t* __restrict__ AT, const ushort_t* __restrict__ BT,
    int pm, int pn, int tid, ushort_t* lds, f32x4 (&acc)[8][4]) {
  const int lane = tid & 63;
  const int wid  = tid >> 6;
  const int wm   = wid & 1;        // wave row (m) 0..1
  const int wn   = wid >> 1;       // wave col (n) 0..3
  const int ks   = p & 1;
  const int b    = (p >> 1) & 1;
  // A frag: row = lane&15, k = (lane>>4)*8 + j  (16x16x32 f16 layout).
  // chunk c = lane>>4 -> slice c>>1, k-half h=c&1, slot = h^((row>>2)&1).
  const int c  = lane >> 4;
  const int rl = lane & 15;
  const int sg = (c & 1) ^ ((rl >> 2) & 1);
  const ushort_t* base = lds + b * 32768 + ks * 8192 + (c >> 1) * 4096 + sg * 8;
  const ushort_t* pa = base + (wm * 128 + rl) * 16;
  const ushort_t* pb = base + 16384 + (wn * 64 + rl) * 16;
  half8 af[8], bf[4];
  // ---- reads 1..12, issue order pinned by SB so counted waits map exactly
  af[0] = *(const half8*)(pa);        SB();
  bf[0] = *(const half8*)(pb);        SB();
  bf[1] = *(const half8*)(pb + 256);  SB();
  bf[2] = *(const half8*)(pb + 512);  SB();
  bf[3] = *(const half8*)(pb + 768);  SB();
  af[1] = *(const half8*)(pa + 256);  SB();
  af[2] = *(const half8*)(pa + 512);  SB();
  af[3] = *(const half8*)(pa + 768);  SB();
  af[4] = *(const half8*)(pa + 1024); SB();
  af[5] = *(const half8*)(pa + 1280); SB();
  af[6] = *(const half8*)(pa + 1536); SB();
  af[7] = *(const half8*)(pa + 1792); SB();
  if constexpr (STG) stage_unit(p + 3, AT, BT, pm, pn, tid, lds);
  __builtin_amdgcn_s_setprio(1);
#define MF(i, j, W)                                                          \
  wait_lgkm<W>();                                                            \
  acc[i][j] = __builtin_amdgcn_mfma_f32_16x16x32_f16(af[i], bf[j], acc[i][j], 0, 0, 0)
#define MROW(i, W)                                                           \
  wait_lgkm<W>();                                                            \
  acc[i][0] = __builtin_amdgcn_mfma_f32_16x16x32_f16(af[i], bf[0], acc[i][0], 0, 0, 0); \
  acc[i][1] = __builtin_amdgcn_mfma_f32_16x16x32_f16(af[i], bf[1], acc[i][1], 0, 0, 0); \
  acc[i][2] = __builtin_amdgcn_mfma_f32_16x16x32_f16(af[i], bf[2], acc[i][2], 0, 0, 0); \
  acc[i][3] = __builtin_amdgcn_mfma_f32_16x16x32_f16(af[i], bf[3], acc[i][3], 0, 0, 0)
  MF(0, 0, 10);
  MF(0, 1, 9);
  MF(0, 2, 8);
  MF(0, 3, 7);
  MROW(1, 6);
  MROW(2, 5);
  MROW(3, 4);
  MROW(4, 3);
  MROW(5, 2);
  MROW(6, 1);
  MROW(7, 0);
#undef MF
#undef MROW
  __builtin_amdgcn_s_setprio(0);
  if constexpr (VN == 8)      asm volatile("s_waitcnt vmcnt(8)" ::: "memory");
  else if constexpr (VN == 4) asm volatile("s_waitcnt vmcnt(4)" ::: "memory");
  else if constexpr (VN == 0) asm volatile("s_waitcnt vmcnt(0)" ::: "memory");
  if constexpr (VN >= 0) {
    __builtin_amdgcn_s_barrier();
    asm volatile("" ::: "memory");     // fence: next phase's ds_reads stay below
  }
}

__global__ __launch_bounds__(512, 2) void gemm256_kernel(
    const ushort_t* __restrict__ XbT, const ushort_t* __restrict__ WtT,
    const float* __restrict__ bias, float* __restrict__ out) {
  __shared__ __align__(16) ushort_t lds[65536];   // 128 KiB, ring of 4 units
  const int tid = threadIdx.x;
  const int pm  = blockIdx.x;          // m fastest: B panel L3-resident
  const int pn  = blockIdx.y;
  const int m0  = pm * 256;
  const int n0  = pn * 256;
  f32x4 acc[8][4] = {};

  // prologue: units 0,1,2 in flight; vmcnt(8) -> unit 0 landed
  stage_unit(0, XbT, WtT, pm, pn, tid, lds);
  stage_unit(1, XbT, WtT, pm, pn, tid, lds);
  stage_unit(2, XbT, WtT, pm, pn, tid, lds);
  asm volatile("s_waitcnt vmcnt(8)" ::: "memory");
  __builtin_amdgcn_s_barrier();
  asm volatile("" ::: "memory");

  // 128 phases = one 32-k unit each. Unroll 4 folds ring indices.
#pragma unroll 4
  for (int p = 0; p < 125; ++p)
    gemm_phase<8, true>(p, XbT, WtT, pm, pn, tid, lds, acc);
  gemm_phase<4,  false>(125, XbT, WtT, pm, pn, tid, lds, acc);
  gemm_phase<0,  false>(126, XbT, WtT, pm, pn, tid, lds, acc);
  gemm_phase<-1, false>(127, XbT, WtT, pm, pn, tid, lds, acc);

  // epilogue: 16x16 C/D layout col=lane&15, row=(lane>>4)*4+reg [m89].
  const int lane = tid & 63;
  const int wm   = (tid >> 6) & 1;
  const int wn   = tid >> 7;
#pragma unroll
  for (int jj = 0; jj < 4; ++jj) {
    int n = n0 + wn * 64 + jj * 16 + (lane & 15);
    float bv = bias[n];
#pragma unroll
    for (int i = 0; i < 8; ++i) {
      int mb = (int)(m0 + wm * 128 + i * 16 + ((lane >> 4) << 2));
#pragma unroll
      for (int r = 0; r < 4; ++r)
        __builtin_nontemporal_store(acc[i][jj][r] + bv,
                                    out + (size_t)(mb + r) * N_DIM + n);
    }
  }
}

// ---------------------------------------------------------------------------
// Fallback GEMM: fully-fused 128x128x64 tile (no workspace) — correctness
// safety net only.
__global__ __launch_bounds__(256) void gemm_fused_kernel(
    const float* __restrict__ Xf,
    const int* __restrict__ qw, const int* __restrict__ qz,
    const float* __restrict__ sc,
    const float* __restrict__ bias, float* __restrict__ out) {
  __shared__ __align__(16) ushort_t lsA[128 * 64];
  __shared__ __align__(16) ushort_t lsB[128 * 64];
  const int tid  = threadIdx.x;
  const int lane = tid & 63;
  const int wid  = tid >> 6;
  const int wm   = wid & 1;
  const int wn   = wid >> 1;
  const int m0   = blockIdx.x * 128;
  const int n0   = blockIdx.y * 128;

  f32x16 acc[2][2] = {};

  for (int kt = 0; kt < K_DIM / 64; ++kt) {
    const int kb = kt * 64;
#pragma unroll
    for (int i = 0; i < 4; ++i) {
      int cid = i * 256 + tid;
      int r = cid >> 3, scol = cid & 7;
      int c = scol ^ (r & 7);
      const float* src = Xf + (size_t)(m0 + r) * K_DIM + kb + c * 8;
      float4 a = *(const float4*)src;
      float4 b = *(const float4*)(src + 4);
      us8 o;
      o[0] = f2h(a.x); o[1] = f2h(a.y); o[2] = f2h(a.z); o[3] = f2h(a.w);
      o[4] = f2h(b.x); o[5] = f2h(b.y); o[6] = f2h(b.z); o[7] = f2h(b.w);
      *(us8*)(lsA + cid * 8) = o;
    }
#pragma unroll
    for (int i = 0; i < 4; ++i) {
      int wi = i * 256 + tid;
      int kl = wi >> 4, cw = wi & 15;
      int k = kb + kl;
      int g = k >> 7;
      int qword = qw[(size_t)k * NP + (n0 >> 3) + cw];
      int zword = qz[g * NP + (n0 >> 3) + cw];
      float4 s0 = *(const float4*)(sc + (size_t)g * N_DIM + n0 + cw * 8);
      float4 s1 = *(const float4*)(sc + (size_t)g * N_DIM + n0 + cw * 8 + 4);
      float sv[8] = {s0.x, s0.y, s0.z, s0.w, s1.x, s1.y, s1.z, s1.w};
#pragma unroll
      for (int j = 0; j < 8; ++j) {
        int nl = cw * 8 + j;
        int q = (qword >> (4 * j)) & 0xF;
        int z = (zword >> (4 * j)) & 0xF;
        lsB[nl * 64 + (((kl >> 3) ^ (nl & 7)) << 3) + (kl & 7)] =
            f2h((float)(q - z) * sv[j]);
      }
    }
    __syncthreads();
#pragma unroll
    for (int ks = 0; ks < 4; ++ks) {
      half8 af[2], bfr[2];
      const int h = lane >> 5;
      const int c = ks * 2 + h;
#pragma unroll
      for (int i = 0; i < 2; ++i) {
        int row = wm * 64 + i * 32 + (lane & 31);
        af[i] = *(const half8*)(lsA + (row * 8 + (c ^ (row & 7))) * 8);
      }
#pragma unroll
      for (int jj = 0; jj < 2; ++jj) {
        int row = wn * 64 + jj * 32 + (lane & 31);
        bfr[jj] = *(const half8*)(lsB + (row * 8 + (c ^ (row & 7))) * 8);
      }
#pragma unroll
      for (int i = 0; i < 2; ++i)
#pragma unroll
        for (int jj = 0; jj < 2; ++jj)
          acc[i][jj] = __builtin_amdgcn_mfma_f32_32x32x16_f16(
              af[i], bfr[jj], acc[i][jj], 0, 0, 0);
    }
    __syncthreads();
  }

#pragma unroll
  for (int jj = 0; jj < 2; ++jj) {
    int n = n0 + wn * 64 + jj * 32 + (lane & 31);
    float bv = bias[n];
#pragma unroll
    for (int i = 0; i < 2; ++i) {
      int mbase = m0 + wm * 64 + i * 32 + ((lane >> 5) << 2);
#pragma unroll
      for (int reg = 0; reg < 16; ++reg) {
        int m = mbase + (reg & 3) + ((reg >> 2) << 3);
        __builtin_nontemporal_store(acc[i][jj][reg] + bv,
                                    out + (size_t)m * N_DIM + n);
      }
    }
  }
}

// ---------------------------------------------------------------------------
extern "C" void kernel_launch(void* const* d_in, const int* in_sizes, int n_in,
                              void* d_out, int out_size, void* d_ws, size_t ws_size,
                              hipStream_t stream) {
  const float* x    = (const float*)d_in[0];
  const int*   qw   = (const int*)d_in[1];
  const int*   qz   = (const int*)d_in[2];
  const float* sc   = (const float*)d_in[3];
  const float* bias = (const float*)d_in[4];
  float*       out  = (float*)d_out;
  // d_in[5] = groupsize (=128, hardcoded)

  const size_t WT_BYTES = (size_t)N_DIM * K_DIM * 2;  // 96 MiB tiled units
  const size_t XB_BYTES = (size_t)M_DIM * K_DIM * 2;  // 32 MiB tiled units
  ushort_t* WtT = (ushort_t*)d_ws;
  ushort_t* XbT = (ushort_t*)((char*)d_ws + WT_BYTES);
  const bool hasWs = ws_size >= WT_BYTES + XB_BYTES;

  if (hasWs) {
    prep_kernel<<<DQ_BLOCKS + CVT_BLOCKS, 256, 0, stream>>>(qw, qz, sc, WtT, x, XbT);
    dim3 grid256(M_DIM / 256, N_DIM / 256);  // (16, 48): m fastest
    gemm256_kernel<<<grid256, 512, 0, stream>>>(XbT, WtT, bias, out);
  } else {
    dim3 grid(M_DIM / 128, N_DIM / 128);
    gemm_fused_kernel<<<grid, 256, 0, stream>>>(x, qw, qz, sc, bias, out);
  }
}